// Round 7
// baseline (3332.149 us; speedup 1.0000x reference)
//
#include <hip/hip_runtime.h>
#include <stdint.h>

typedef __bf16 bf16_t;
typedef __bf16 bf16x8 __attribute__((ext_vector_type(8)));
typedef __bf16 bf16x4 __attribute__((ext_vector_type(4)));
typedef float  f32x4  __attribute__((ext_vector_type(4)));

#define DEVINL __device__ __forceinline__

DEVINL void gload_lds16(const bf16_t* g, bf16_t* l) {
  __builtin_amdgcn_global_load_lds(
      (__attribute__((address_space(1))) void*)g,
      (__attribute__((address_space(3))) void*)l,
      16, 0, 0);
}
DEVINL void memfence() { asm volatile("" ::: "memory"); }
DEVINL void bar() { memfence(); __builtin_amdgcn_s_barrier(); memfence(); }
#define VMCNT(n) asm volatile("s_waitcnt vmcnt(" #n ")" ::: "memory")

// ---------------- elementwise glue ----------------

__global__ void __launch_bounds__(256) k_w_to_bf16(const float* __restrict__ w0,
                                                   const float* __restrict__ w1,
                                                   const float* __restrict__ w2,
                                                   const float* __restrict__ w3,
                                                   bf16_t* __restrict__ dst) {
  const float* src = (blockIdx.y == 0) ? w0 : (blockIdx.y == 1) ? w1 : (blockIdx.y == 2) ? w2 : w3;
  int i = blockIdx.x * 256 + threadIdx.x;
  float4 v = ((const float4*)src)[i];
  bf16x4 o;
  o[0] = (bf16_t)v.x; o[1] = (bf16_t)v.y; o[2] = (bf16_t)v.z; o[3] = (bf16_t)v.w;
  *(bf16x4*)(dst + ((long)blockIdx.y << 20) + (long)i * 4) = o;
}

__global__ void __launch_bounds__(256) k_addpos(const float* __restrict__ x,
                                                const float* __restrict__ pos,
                                                bf16_t* __restrict__ out) {
  long i = ((long)blockIdx.x * 256 + threadIdx.x) * 4;
  int d = (int)(i & 1023);
  int s = (int)((i >> 10) & 2047);
  float4 a = *(const float4*)(x + i);
  float4 p = *(const float4*)(pos + ((long)s << 10) + d);
  bf16x4 o;
  o[0] = (bf16_t)(a.x + p.x); o[1] = (bf16_t)(a.y + p.y);
  o[2] = (bf16_t)(a.z + p.z); o[3] = (bf16_t)(a.w + p.w);
  *(bf16x4*)(out + i) = o;
}

// one wave per 1024-wide row
__global__ void __launch_bounds__(64) k_l2norm(const bf16_t* __restrict__ in,
                                               bf16_t* __restrict__ out) {
  const long row = blockIdx.x;
  const int lane = threadIdx.x;
  const bf16_t* p = in + (row << 10) + lane * 16;
  bf16x8 v0 = *(const bf16x8*)(p);
  bf16x8 v1 = *(const bf16x8*)(p + 8);
  float ss = 0.f;
#pragma unroll
  for (int j = 0; j < 8; ++j) {
    float a = (float)v0[j], b = (float)v1[j];
    ss += a * a + b * b;
  }
#pragma unroll
  for (int off = 32; off; off >>= 1) ss += __shfl_xor(ss, off);
  const float sc = 1.f / (sqrtf(ss) + 1e-6f);
  bf16x8 o0, o1;
#pragma unroll
  for (int j = 0; j < 8; ++j) {
    o0[j] = (bf16_t)((float)v0[j] * sc);
    o1[j] = (bf16_t)((float)v1[j] * sc);
  }
  bf16_t* q = out + (row << 10) + lane * 16;
  *(bf16x8*)(q) = o0;
  *(bf16x8*)(q + 8) = o1;
}

// per-batch transpose [2048][1024] -> [1024][2048]
__global__ void __launch_bounds__(256) k_transpose(const bf16_t* __restrict__ Y,
                                                   bf16_t* __restrict__ Yt) {
  const int b = blockIdx.z;
  const int t0 = blockIdx.x * 64;
  const int d0 = blockIdx.y * 64;
  const bf16_t* src = Y + ((long)b << 21);
  bf16_t* dst = Yt + ((long)b << 21);
  __shared__ bf16_t tile[64][80];
  const int tid = threadIdx.x;
  const int r = tid >> 3;
  const int c = (tid & 7) * 8;
#pragma unroll
  for (int ph = 0; ph < 2; ++ph) {
    bf16x8 v = *(const bf16x8*)(src + (long)(t0 + r + ph * 32) * 1024 + d0 + c);
    *(bf16x8*)(&tile[r + ph * 32][c]) = v;
  }
  __syncthreads();
#pragma unroll
  for (int ph = 0; ph < 2; ++ph) {
    bf16x8 o;
#pragma unroll
    for (int j = 0; j < 8; ++j) o[j] = tile[c + j][r + ph * 32];
    *(bf16x8*)(dst + (long)(d0 + r + ph * 32) * 2048 + t0 + c) = o;
  }
}

// ---------------- 256x256 GEMM, BK=32, 64 KiB LDS -> 2 blocks/CU ----------------
// C[m,n] = sum_k A[m,k]*B[n,k]. 512 threads = 8 waves (2M x 4N), per-wave 128x64.
// LDS: buf b at b*32768; A halves at +h*8192; B at +16384+h*8192. Rows are 64 B;
// bank swizzle: k-granule ^= (row>>1)&3, applied at stage-source AND frag-read.
// 2 phases/K-tile, counted vmcnt(2) once per tile (in-flight: B(t+1) after drain).
template <int RELU, typename OUT_T>
__global__ void __launch_bounds__(512, 4)
k_gemm256(const bf16_t* __restrict__ A, const bf16_t* __restrict__ Bm,
          OUT_T* __restrict__ C, int N, int K,
          long sA, long sB, long sC, int gy) {
  __shared__ char lds[65536];

  const int tid = threadIdx.x;
  const int nwg = gridDim.x;              // multiple of 8 for all our launches
  const int wg = (blockIdx.x & 7) * (nwg >> 3) + (blockIdx.x >> 3);  // XCD swizzle
  const int bm = wg / gy, bn = wg % gy;
  A  += (long)blockIdx.y * sA;
  Bm += (long)blockIdx.y * sB;
  C  += (long)blockIdx.y * sC;
  const long row0 = (long)bm * 256, col0 = (long)bn * 256;

  // staging: one 16B chunk per thread per 128x32 half-tile (8 KiB)
  const int sr = tid >> 2;                        // row in half 0..127
  const int sg = (tid & 3) ^ ((sr >> 1) & 3);     // swizzled source k-granule
  const long gsrc = (long)sr * K + sg * 8;        // element offset
  const int ldst = tid * 16;                      // linear LDS byte dest

  auto stageA = [&](int t, int h) {
    const bf16_t* s = A + (row0 + h * 128) * (long)K + (long)t * 32 + gsrc;
    gload_lds16(s, (bf16_t*)(lds + (t & 1) * 32768 + h * 8192 + ldst));
  };
  auto stageB = [&](int t, int h) {
    const bf16_t* s = Bm + (col0 + h * 128) * (long)K + (long)t * 32 + gsrc;
    gload_lds16(s, (bf16_t*)(lds + (t & 1) * 32768 + 16384 + h * 8192 + ldst));
  };

  const int lane = tid & 63;
  const int w = tid >> 6, wm = w >> 2, wn = w & 3;
  const int l15 = lane & 15;
  const int lh = (lane >> 4) << 4;       // logical k-granule byte 0..48

  auto fragA = [&](int b, int mf) -> bf16x8 {
    int rl = mf * 16 + l15;
    int addr = b * 32768 + wm * 8192 + rl * 64 + (lh ^ (((rl >> 1) & 3) << 4));
    return *(const bf16x8*)(lds + addr);
  };
  auto fragB = [&](int b, int nf) -> bf16x8 {
    int rb = (wn & 1) * 64 + nf * 16 + l15;
    int addr = b * 32768 + 16384 + (wn >> 1) * 8192 + rb * 64 + (lh ^ (((rb >> 1) & 3) << 4));
    return *(const bf16x8*)(lds + addr);
  };

  f32x4 acc[8][4];
#pragma unroll
  for (int i = 0; i < 8; ++i)
#pragma unroll
    for (int j = 0; j < 4; ++j) acc[i][j] = {0.f, 0.f, 0.f, 0.f};

  // prologue: stage A(0), B(0), B(1); drain A(0)+B(0), leave B(1) in flight
  stageA(0, 0); stageA(0, 1); stageB(0, 0); stageB(0, 1);
  stageB(1, 0); stageB(1, 1);
  VMCNT(2);
  bar();

  const int nt = K >> 5;   // >= 32 for our shapes
  bf16x8 alo[4], ahi[4], blo[2], bhi[2];
#pragma unroll 2
  for (int t = 0; t < nt; ++t) {
    const int b = t & 1;

    // ---- phase 1: read alo/blo/bhi (8 reads), stage A(t+1); MFMA lo-half ----
#pragma unroll
    for (int mf = 0; mf < 4; ++mf) alo[mf] = fragA(b, mf);
#pragma unroll
    for (int nf = 0; nf < 2; ++nf) blo[nf] = fragB(b, nf);
#pragma unroll
    for (int nf = 0; nf < 2; ++nf) bhi[nf] = fragB(b, nf + 2);
    if (t + 1 < nt) { stageA(t + 1, 0); stageA(t + 1, 1); }
    bar();
    __builtin_amdgcn_s_setprio(1);
#pragma unroll
    for (int mf = 0; mf < 4; ++mf) {
#pragma unroll
      for (int nf = 0; nf < 2; ++nf)
        acc[mf][nf] = __builtin_amdgcn_mfma_f32_16x16x32_bf16(alo[mf], blo[nf], acc[mf][nf], 0, 0, 0);
#pragma unroll
      for (int nf = 0; nf < 2; ++nf)
        acc[mf][nf + 2] = __builtin_amdgcn_mfma_f32_16x16x32_bf16(alo[mf], bhi[nf], acc[mf][nf + 2], 0, 0, 0);
    }
    __builtin_amdgcn_s_setprio(0);
    bar();

    // ---- phase 2: read ahi (4 reads), stage B(t+2); MFMA hi-half; counted vmcnt ----
#pragma unroll
    for (int mf = 0; mf < 4; ++mf) ahi[mf] = fragA(b, mf + 4);
    if (t + 2 < nt) { stageB(t + 2, 0); stageB(t + 2, 1); }
    bar();
    __builtin_amdgcn_s_setprio(1);
#pragma unroll
    for (int mf = 0; mf < 4; ++mf) {
#pragma unroll
      for (int nf = 0; nf < 2; ++nf)
        acc[mf + 4][nf] = __builtin_amdgcn_mfma_f32_16x16x32_bf16(ahi[mf], blo[nf], acc[mf + 4][nf], 0, 0, 0);
#pragma unroll
      for (int nf = 0; nf < 2; ++nf)
        acc[mf + 4][nf + 2] = __builtin_amdgcn_mfma_f32_16x16x32_bf16(ahi[mf], bhi[nf], acc[mf + 4][nf + 2], 0, 0, 0);
    }
    __builtin_amdgcn_s_setprio(0);
    // steady: drain B(t+1)+A(t+1), leave B(t+2) (2 loads) in flight
    if (t + 2 < nt) VMCNT(2); else VMCNT(0);
    bar();
  }

  // epilogue: direct store. C/D layout col=lane&15, row=(lane>>4)*4+reg [m89-verified]
  const int crow = (lane >> 4) * 4;
#pragma unroll
  for (int mf = 0; mf < 8; ++mf) {
    const long gr = row0 + wm * 128 + mf * 16 + crow;
#pragma unroll
    for (int nf = 0; nf < 4; ++nf) {
      const long gc = col0 + wn * 64 + nf * 16 + l15;
#pragma unroll
      for (int v = 0; v < 4; ++v) {
        float val = acc[mf][nf][v];
        if (RELU) val = fmaxf(val, 0.f);
        C[(gr + v) * N + gc] = (OUT_T)val;
      }
    }
  }
}

// ---------------- launch ----------------

extern "C" void kernel_launch(void* const* d_in, const int* in_sizes, int n_in,
                              void* d_out, int out_size, void* d_ws, size_t ws_size,
                              hipStream_t stream) {
  const float* x   = (const float*)d_in[0];
  const float* pos = (const float*)d_in[1];
  const float* w0  = (const float*)d_in[2];
  const float* w1  = (const float*)d_in[3];
  const float* w2  = (const float*)d_in[4];
  const float* w3  = (const float*)d_in[5];
  float* out = (float*)d_out;

  const int S = 2048, D = 1024;
  const long MS = 32768;
  const long actElems = MS * D;

  char* ws = (char*)d_ws;
  bf16_t* w0b  = (bf16_t*)(ws + 0l);
  bf16_t* w1b  = (bf16_t*)(ws + (2l << 20));
  bf16_t* w2b  = (bf16_t*)(ws + (4l << 20));
  bf16_t* w3b  = (bf16_t*)(ws + (6l << 20));
  bf16_t* buf1 = (bf16_t*)(ws + (8l << 20));    // 64 MiB
  bf16_t* buf2 = (bf16_t*)(ws + (72l << 20));   // 64 MiB
  bf16_t* gbuf = (bf16_t*)d_out;                // 32 MiB Gram scratch, dead before final GEMM

  k_w_to_bf16<<<dim3(1024, 4), dim3(256), 0, stream>>>(w0, w1, w2, w3, w0b);

  k_addpos<<<dim3((unsigned)(actElems / 4 / 256)), dim3(256), 0, stream>>>(x, pos, buf1);

  // enc MLP: M=32768 N=1024 K=1024 -> 128*4 = 512 wgs (2 blocks/CU)
  k_gemm256<1, bf16_t><<<dim3(512, 1), dim3(512), 0, stream>>>(buf1, w0b, buf2, 1024, 1024, 0, 0, 0, 4);
  k_gemm256<1, bf16_t><<<dim3(512, 1), dim3(512), 0, stream>>>(buf2, w1b, buf1, 1024, 1024, 0, 0, 0, 4);

  k_l2norm<<<dim3((unsigned)MS), dim3(64), 0, stream>>>(buf1, buf2);     // buf2 = Y
  k_transpose<<<dim3(32, 16, 16), dim3(256), 0, stream>>>(buf2, buf1);   // buf1 = Yt [16][1024][2048]

  // Gram: G_b = Yt_b · Yt_b^T  (M=N=1024, K=2048)  — att = (Y·Yᵀ)·Y = Y·(YᵀY) = Y·G
  k_gemm256<0, bf16_t><<<dim3(16, 16), dim3(512), 0, stream>>>(
      buf1, buf1, gbuf, 1024, 2048, (long)D * S, (long)D * S, (long)D * D, 4);

  // att_b = Y_b · G_b  (BT-form via symmetry: C[s,d] = sum_e Y[s,e]*G[d,e]), M=2048 N=1024 K=1024
  k_gemm256<0, bf16_t><<<dim3(32, 16), dim3(512), 0, stream>>>(
      buf2, gbuf, buf1, 1024, 1024, (long)S * D, (long)D * D, (long)S * D, 4);

  // dec MLP
  k_gemm256<1, bf16_t><<<dim3(512, 1), dim3(512), 0, stream>>>(buf1, w2b, buf2, 1024, 1024, 0, 0, 0, 4);
  k_gemm256<1, float ><<<dim3(512, 1), dim3(512), 0, stream>>>(buf2, w3b, out, 1024, 1024, 0, 0, 0, 4);
}

// Round 8
// 478.321 us; speedup vs baseline: 6.9663x; 6.9663x over previous
//
#include <hip/hip_runtime.h>
#include <stdint.h>

typedef __bf16 bf16_t;
typedef __bf16 bf16x8 __attribute__((ext_vector_type(8)));
typedef __bf16 bf16x4 __attribute__((ext_vector_type(4)));
typedef float  f32x4  __attribute__((ext_vector_type(4)));

#define DEVINL __device__ __forceinline__

DEVINL void gload_lds16(const bf16_t* g, bf16_t* l) {
  __builtin_amdgcn_global_load_lds(
      (__attribute__((address_space(1))) void*)g,
      (__attribute__((address_space(3))) void*)l,
      16, 0, 0);
}
DEVINL void memfence() { asm volatile("" ::: "memory"); }
DEVINL void bar() { memfence(); __builtin_amdgcn_s_barrier(); memfence(); }

// ---------------- elementwise glue ----------------

__global__ void __launch_bounds__(256) k_w_to_bf16(const float* __restrict__ w0,
                                                   const float* __restrict__ w1,
                                                   const float* __restrict__ w2,
                                                   const float* __restrict__ w3,
                                                   bf16_t* __restrict__ dst) {
  const float* src = (blockIdx.y == 0) ? w0 : (blockIdx.y == 1) ? w1 : (blockIdx.y == 2) ? w2 : w3;
  int i = blockIdx.x * 256 + threadIdx.x;
  float4 v = ((const float4*)src)[i];
  bf16x4 o;
  o[0] = (bf16_t)v.x; o[1] = (bf16_t)v.y; o[2] = (bf16_t)v.z; o[3] = (bf16_t)v.w;
  *(bf16x4*)(dst + ((long)blockIdx.y << 20) + (long)i * 4) = o;
}

__global__ void __launch_bounds__(256) k_addpos(const float* __restrict__ x,
                                                const float* __restrict__ pos,
                                                bf16_t* __restrict__ out) {
  long i = ((long)blockIdx.x * 256 + threadIdx.x) * 4;
  int d = (int)(i & 1023);
  int s = (int)((i >> 10) & 2047);
  float4 a = *(const float4*)(x + i);
  float4 p = *(const float4*)(pos + ((long)s << 10) + d);
  bf16x4 o;
  o[0] = (bf16_t)(a.x + p.x); o[1] = (bf16_t)(a.y + p.y);
  o[2] = (bf16_t)(a.z + p.z); o[3] = (bf16_t)(a.w + p.w);
  *(bf16x4*)(out + i) = o;
}

// one wave per 1024-wide row
__global__ void __launch_bounds__(64) k_l2norm(const bf16_t* __restrict__ in,
                                               bf16_t* __restrict__ out) {
  const long row = blockIdx.x;
  const int lane = threadIdx.x;
  const bf16_t* p = in + (row << 10) + lane * 16;
  bf16x8 v0 = *(const bf16x8*)(p);
  bf16x8 v1 = *(const bf16x8*)(p + 8);
  float ss = 0.f;
#pragma unroll
  for (int j = 0; j < 8; ++j) {
    float a = (float)v0[j], b = (float)v1[j];
    ss += a * a + b * b;
  }
#pragma unroll
  for (int off = 32; off; off >>= 1) ss += __shfl_xor(ss, off);
  const float sc = 1.f / (sqrtf(ss) + 1e-6f);
  bf16x8 o0, o1;
#pragma unroll
  for (int j = 0; j < 8; ++j) {
    o0[j] = (bf16_t)((float)v0[j] * sc);
    o1[j] = (bf16_t)((float)v1[j] * sc);
  }
  bf16_t* q = out + (row << 10) + lane * 16;
  *(bf16x8*)(q) = o0;
  *(bf16x8*)(q + 8) = o1;
}

// per-batch transpose [2048][1024] -> [1024][2048]
__global__ void __launch_bounds__(256) k_transpose(const bf16_t* __restrict__ Y,
                                                   bf16_t* __restrict__ Yt) {
  const int b = blockIdx.z;
  const int t0 = blockIdx.x * 64;
  const int d0 = blockIdx.y * 64;
  const bf16_t* src = Y + ((long)b << 21);
  bf16_t* dst = Yt + ((long)b << 21);
  __shared__ bf16_t tile[64][80];
  const int tid = threadIdx.x;
  const int r = tid >> 3;
  const int c = (tid & 7) * 8;
#pragma unroll
  for (int ph = 0; ph < 2; ++ph) {
    bf16x8 v = *(const bf16x8*)(src + (long)(t0 + r + ph * 32) * 1024 + d0 + c);
    *(bf16x8*)(&tile[r + ph * 32][c]) = v;
  }
  __syncthreads();
#pragma unroll
  for (int ph = 0; ph < 2; ++ph) {
    bf16x8 o;
#pragma unroll
    for (int j = 0; j < 8; ++j) o[j] = tile[c + j][r + ph * 32];
    *(bf16x8*)(dst + (long)(d0 + r + ph * 32) * 2048 + t0 + c) = o;
  }
}

// ---------------- 256x256 8-phase GEMM: C[m,n] = sum_k A[m,k]*B[n,k] ----------------
// (round-2 proven schedule, verbatim; direct epilogue)
template <int RELU, typename OUT_T>
__global__ void __launch_bounds__(512, 2)
k_gemm256(const bf16_t* __restrict__ A, const bf16_t* __restrict__ Bm,
          OUT_T* __restrict__ C, int N, int K,
          long sA, long sB, long sC, int gy) {
  __shared__ char lds[131072];

  const int tid = threadIdx.x;
  const int nwg = gridDim.x;              // multiple of 8 for all our launches
  const int wg = (blockIdx.x & 7) * (nwg >> 3) + (blockIdx.x >> 3);  // XCD swizzle
  const int bm = wg / gy, bn = wg % gy;
  A  += (long)blockIdx.y * sA;
  Bm += (long)blockIdx.y * sB;
  C  += (long)blockIdx.y * sC;
  const long row0 = (long)bm * 256, col0 = (long)bn * 256;

  // staging: chunk i*512+tid covers a 128x64 half-tile (16 KiB); source pre-swizzled
  const int r0 = tid >> 3, r1 = (tid + 512) >> 3;
  const int cb0 = ((tid & 7) << 4) ^ ((r0 & 7) << 4);
  const int cb1 = ((tid & 7) << 4) ^ ((r1 & 7) << 4);
  const long go0 = (long)r0 * K + (cb0 >> 1);
  const long go1 = (long)r1 * K + (cb1 >> 1);
  const int lo0 = tid * 16, lo1 = (tid + 512) * 16;

  auto stageA = [&](int t, int h) {
    const bf16_t* s = A + (row0 + h * 128) * (long)K + (long)t * 64;
    char* dbase = lds + (t & 1) * 65536 + h * 16384;
    gload_lds16(s + go0, (bf16_t*)(dbase + lo0));
    gload_lds16(s + go1, (bf16_t*)(dbase + lo1));
  };
  auto stageB = [&](int t, int h) {
    const bf16_t* s = Bm + (col0 + h * 128) * (long)K + (long)t * 64;
    char* dbase = lds + (t & 1) * 65536 + 32768 + h * 16384;
    gload_lds16(s + go0, (bf16_t*)(dbase + lo0));
    gload_lds16(s + go1, (bf16_t*)(dbase + lo1));
  };

  const int lane = tid & 63;
  const int w = tid >> 6, wm = w >> 2, wn = w & 3;
  const int l15 = lane & 15;
  const int lh = (lane >> 4) << 4;       // 0,16,32,48 byte k-offset

  auto fragA = [&](int b, int mf, int ks) -> bf16x8 {
    int rl = mf * 16 + l15;
    int addr = b * 65536 + wm * 16384 + rl * 128 + ks * 64 + lh;
    addr ^= (rl & 7) << 4;
    return *(const bf16x8*)(lds + addr);
  };
  auto fragB = [&](int b, int nf, int ks) -> bf16x8 {
    int cl = (wn & 1) * 64 + nf * 16 + l15;
    int addr = b * 65536 + 32768 + (wn >> 1) * 16384 + cl * 128 + ks * 64 + lh;
    addr ^= (cl & 7) << 4;
    return *(const bf16x8*)(lds + addr);
  };

  f32x4 acc[8][4];
#pragma unroll
  for (int i = 0; i < 8; ++i)
#pragma unroll
    for (int j = 0; j < 4; ++j) acc[i][j] = {0.f, 0.f, 0.f, 0.f};

  // prologue: stage tiles 0 and 1 fully
  stageA(0, 0); stageA(0, 1); stageB(0, 0); stageB(0, 1);
  stageA(1, 0); stageA(1, 1); stageB(1, 0); stageB(1, 1);
  asm volatile("s_waitcnt vmcnt(8)" ::: "memory");   // tile 0 landed, tile 1 in flight
  bar();

  const int nt = K >> 6;
#pragma unroll 2
  for (int t = 0; t < nt; ++t) {
    const int b = t & 1;
    bf16x8 a0[4][2], a1[4][2], b0[2][2], b1[2][2];

    // ---- phase 1: read A-low + B-low, stage Ah0(t+1), MFMA Q(lo,lo) ----
#pragma unroll
    for (int mf = 0; mf < 4; ++mf)
#pragma unroll
      for (int ks = 0; ks < 2; ++ks) a0[mf][ks] = fragA(b, mf, ks);
#pragma unroll
    for (int nf = 0; nf < 2; ++nf)
#pragma unroll
      for (int ks = 0; ks < 2; ++ks) b0[nf][ks] = fragB(b, nf, ks);
    if (t >= 1 && t + 1 < nt) stageA(t + 1, 0);
    bar();
    __builtin_amdgcn_s_setprio(1);
#pragma unroll
    for (int mf = 0; mf < 4; ++mf)
#pragma unroll
      for (int nf = 0; nf < 2; ++nf)
#pragma unroll
        for (int ks = 0; ks < 2; ++ks)
          acc[mf][nf] = __builtin_amdgcn_mfma_f32_16x16x32_bf16(a0[mf][ks], b0[nf][ks], acc[mf][nf], 0, 0, 0);
    __builtin_amdgcn_s_setprio(0);
    bar();

    // ---- phase 2: read B-high, stage Ah1(t+1), MFMA Q(lo,hi) ----
#pragma unroll
    for (int nf = 0; nf < 2; ++nf)
#pragma unroll
      for (int ks = 0; ks < 2; ++ks) b1[nf][ks] = fragB(b, nf + 2, ks);
    if (t >= 1 && t + 1 < nt) stageA(t + 1, 1);
    bar();
    __builtin_amdgcn_s_setprio(1);
#pragma unroll
    for (int mf = 0; mf < 4; ++mf)
#pragma unroll
      for (int nf = 0; nf < 2; ++nf)
#pragma unroll
        for (int ks = 0; ks < 2; ++ks)
          acc[mf][nf + 2] = __builtin_amdgcn_mfma_f32_16x16x32_bf16(a0[mf][ks], b1[nf][ks], acc[mf][nf + 2], 0, 0, 0);
    __builtin_amdgcn_s_setprio(0);
    bar();

    // ---- phase 3: read A-high, stage Bh0(t+2), MFMA Q(hi,lo) ----
#pragma unroll
    for (int mf = 0; mf < 4; ++mf)
#pragma unroll
      for (int ks = 0; ks < 2; ++ks) a1[mf][ks] = fragA(b, mf + 4, ks);
    if (t + 2 < nt) stageB(t + 2, 0);
    bar();
    __builtin_amdgcn_s_setprio(1);
#pragma unroll
    for (int mf = 0; mf < 4; ++mf)
#pragma unroll
      for (int nf = 0; nf < 2; ++nf)
#pragma unroll
        for (int ks = 0; ks < 2; ++ks)
          acc[mf + 4][nf] = __builtin_amdgcn_mfma_f32_16x16x32_bf16(a1[mf][ks], b0[nf][ks], acc[mf + 4][nf], 0, 0, 0);
    __builtin_amdgcn_s_setprio(0);
    bar();

    // ---- phase 4: stage Bh1(t+2), MFMA Q(hi,hi), counted vmcnt ----
    if (t + 2 < nt) stageB(t + 2, 1);
    bar();
    __builtin_amdgcn_s_setprio(1);
#pragma unroll
    for (int mf = 0; mf < 4; ++mf)
#pragma unroll
      for (int nf = 0; nf < 2; ++nf)
#pragma unroll
        for (int ks = 0; ks < 2; ++ks)
          acc[mf + 4][nf + 2] = __builtin_amdgcn_mfma_f32_16x16x32_bf16(a1[mf][ks], b1[nf][ks], acc[mf + 4][nf + 2], 0, 0, 0);
    __builtin_amdgcn_s_setprio(0);
    // steady state: leave Bh0/Bh1(t+2) (4 loads) in flight; tile t+1 fully landed.
    if (t + 2 < nt) asm volatile("s_waitcnt vmcnt(4)" ::: "memory");
    else            asm volatile("s_waitcnt vmcnt(0)" ::: "memory");
    bar();
  }

  // epilogue: C/D layout col=lane&15, row=(lane>>4)*4+reg  [m89-verified]
  const int crow = (lane >> 4) * 4;
#pragma unroll
  for (int mf = 0; mf < 8; ++mf) {
    const long gr = row0 + wm * 128 + mf * 16 + crow;
#pragma unroll
    for (int nf = 0; nf < 4; ++nf) {
      const long gc = col0 + wn * 64 + nf * 16 + l15;
#pragma unroll
      for (int v = 0; v < 4; ++v) {
        float val = acc[mf][nf][v];
        if (RELU) val = fmaxf(val, 0.f);
        C[(gr + v) * N + gc] = (OUT_T)val;
      }
    }
  }
}

// ---------------- launch ----------------

extern "C" void kernel_launch(void* const* d_in, const int* in_sizes, int n_in,
                              void* d_out, int out_size, void* d_ws, size_t ws_size,
                              hipStream_t stream) {
  const float* x   = (const float*)d_in[0];
  const float* pos = (const float*)d_in[1];
  const float* w0  = (const float*)d_in[2];
  const float* w1  = (const float*)d_in[3];
  const float* w2  = (const float*)d_in[4];
  const float* w3  = (const float*)d_in[5];
  float* out = (float*)d_out;

  const int S = 2048, D = 1024;
  const long MS = 32768;
  const long actElems = MS * D;

  char* ws = (char*)d_ws;
  bf16_t* w0b  = (bf16_t*)(ws + 0l);
  bf16_t* w1b  = (bf16_t*)(ws + (2l << 20));
  bf16_t* w2b  = (bf16_t*)(ws + (4l << 20));
  bf16_t* w3b  = (bf16_t*)(ws + (6l << 20));
  bf16_t* buf1 = (bf16_t*)(ws + (8l << 20));    // 64 MiB
  bf16_t* buf2 = (bf16_t*)(ws + (72l << 20));   // 64 MiB
  // d_out (128 MiB fp32) doubles as scratch, dead until the final GEMM writes it:
  bf16_t* gbuf  = (bf16_t*)d_out;                        // G  [16][1024][1024] bf16, 32 MiB
  bf16_t* htbuf = (bf16_t*)((char*)d_out + (32l << 20)); // Ht [16][1024][1024] bf16, 32 MiB

  k_w_to_bf16<<<dim3(1024, 4), dim3(256), 0, stream>>>(w0, w1, w2, w3, w0b);

  k_addpos<<<dim3((unsigned)(actElems / 4 / 256)), dim3(256), 0, stream>>>(x, pos, buf1);

  // enc MLP: M=32768 N=1024 K=1024 -> 128*4 = 512 wgs
  k_gemm256<1, bf16_t><<<dim3(512, 1), dim3(512), 0, stream>>>(buf1, w0b, buf2, 1024, 1024, 0, 0, 0, 4);
  k_gemm256<1, bf16_t><<<dim3(512, 1), dim3(512), 0, stream>>>(buf2, w1b, buf1, 1024, 1024, 0, 0, 0, 4);

  k_l2norm<<<dim3((unsigned)MS), dim3(64), 0, stream>>>(buf1, buf2);     // buf2 = Y
  k_transpose<<<dim3(32, 16, 16), dim3(256), 0, stream>>>(buf2, buf1);   // buf1 = Yt [16][1024][2048]

  // Gram: G_b = Yt_b · Yt_b^T  (M=N=1024, K=2048) — att = (Y·Yᵀ)·Y = Y·(YᵀY) = Y·G
  k_gemm256<0, bf16_t><<<dim3(16, 16), dim3(512), 0, stream>>>(
      buf1, buf1, gbuf, 1024, 2048, (long)D * S, (long)D * S, (long)D * D, 4);

  // Decoder associativity: dec1 = ReLU(att·W2ᵀ) = ReLU(Y·(G·W2ᵀ)).
  // Ht_b[e,d] = Σ_f W2[e,f]·G_b[d,f]  (BT form; G symmetric), M=N=K=1024
  k_gemm256<0, bf16_t><<<dim3(16, 16), dim3(512), 0, stream>>>(
      w2b, gbuf, htbuf, 1024, 1024, 0, (long)D * D, (long)D * D, 4);

  // dec1_b[s,e] = ReLU( Σ_d Y_b[s,d]·Ht_b[e,d] ), M=2048 N=1024 K=1024
  k_gemm256<1, bf16_t><<<dim3(32, 16), dim3(512), 0, stream>>>(
      buf2, htbuf, buf1, 1024, 1024, (long)S * D, (long)D * D, (long)S * D, 4);

  // dec2: M=32768 N=1024 K=1024, fp32 out
  k_gemm256<1, float ><<<dim3(512, 1), dim3(512), 0, stream>>>(buf1, w3b, out, 1024, 1024, 0, 0, 0, 4);
}